// Round 6
// baseline (302.007 us; speedup 1.0000x reference)
//
#include <hip/hip_runtime.h>
#include <hip/hip_bf16.h>
#include <cstdint>
#include <cstddef>

#define NB 2
#define NH 8
#define BHN 16          // NB*NH
#define NN 3072         // tokens
#define CC 256          // channels
#define DD 32           // head dim
#define OUTW 3104       // NN + DD
#define VW 48           // padded v2p width (38 -> 48)
#define KP 384          // NH*VW, padded K for proj GEMM

typedef __attribute__((ext_vector_type(8))) __bf16 bf16x8;
typedef __attribute__((ext_vector_type(4))) short short4v;
typedef __attribute__((ext_vector_type(4))) float f32x4;

static __device__ __forceinline__ unsigned short f2bf(float f) {
    __hip_bfloat16 h = __float2bfloat16(f);
    return *reinterpret_cast<unsigned short*>(&h);
}

static __device__ __forceinline__ bf16x8 ldb8(const unsigned short* p) {
    return *(const bf16x8*)p;
}

static __device__ __forceinline__ f32x4 mfma16(bf16x8 a, bf16x8 b, f32x4 c) {
    return __builtin_amdgcn_mfma_f32_16x16x32_bf16(a, b, c, 0, 0, 0);
}

static __device__ __forceinline__ float bfhi2f(unsigned u) {
    union { unsigned u; float f; } v; v.u = u & 0xffff0000u; return v.f;
}
static __device__ __forceinline__ float bflo2f(unsigned u) {
    union { unsigned u; float f; } v; v.u = u << 16; return v.f;
}

// ---------------------------------------------------------------------------
// prep
// ---------------------------------------------------------------------------
__global__ __launch_bounds__(256) void prep_kernel(
    const float* __restrict__ x1, const float* __restrict__ x2,
    const float* __restrict__ Wq, const float* __restrict__ Wkv,
    const float* __restrict__ Wpf,
    unsigned short* __restrict__ x1b, unsigned short* __restrict__ x2b,
    unsigned short* __restrict__ Wt, unsigned short* __restrict__ Wpft,
    unsigned short* __restrict__ v2pT)
{
    int i = blockIdx.x * 256 + threadIdx.x;
    const int S_X = NB * NN * CC;
    if (i < S_X) { x1b[i] = f2bf(x1[i]); return; }
    i -= S_X;
    if (i < S_X) { x2b[i] = f2bf(x2[i]); return; }
    i -= S_X;
    const int S_WT = 768 * CC;
    if (i < S_WT) {
        int j = i >> 8, kk = i & 255;
        float w = (j < 256) ? Wq[kk * 256 + j] : Wkv[kk * 512 + (j - 256)];
        Wt[i] = f2bf(w);
        return;
    }
    i -= S_WT;
    const int S_WP = 256 * KP;
    if (i < S_WP) {
        int c2 = i / KP, t = i - c2 * KP;
        int h = t / VW, cc = t - h * VW;
        unsigned short v = 0;
        if (cc < 38) v = f2bf(Wpf[(h * 38 + cc) * 256 + c2]);
        Wpft[i] = v;
        return;
    }
    i -= S_WP;
    const int S_POS = BHN * 16 * NN;
    if (i < S_POS) {
        int n = i % NN;
        int r = i / NN;
        int bh = r >> 4;
        int c = (r & 15) + 32;
        float val = 0.f;
        if (c < 38) {
            float p3 = -1.f + 2.f * (float)(n % 48) / 47.f;
            float p4 = -1.f + 2.f * (float)(n / 48) / 63.f;
            float pv[6] = { p3 * p3, p4 * p4, p3 * p4, p3, p4, 1.f };
            val = pv[c - 32];
        }
        v2pT[((size_t)bh * VW + c) * NN + n] = f2bf(val);
    }
}

// ---------------------------------------------------------------------------
// qkv
// ---------------------------------------------------------------------------
__global__ __launch_bounds__(256) void qkv_kernel(
    const unsigned short* __restrict__ x1b, const unsigned short* __restrict__ x2b,
    const unsigned short* __restrict__ Wt,
    unsigned short* __restrict__ qbh, unsigned short* __restrict__ kbh,
    unsigned short* __restrict__ v2pT)
{
    int rt = blockIdx.x, ct = blockIdx.y;
    int wv = threadIdx.x >> 6, lane = threadIdx.x & 63;
    int g = lane >> 4, q = lane & 15;
    int row0 = rt * 64 + wv * 16;
    const unsigned short* A = (ct < 4) ? x1b : x2b;
    const unsigned short* arow = A + (size_t)(row0 + q) * CC + g * 8;
    const unsigned short* brow = Wt + (size_t)(ct * 64 + q) * CC + g * 8;
    f32x4 acc[4];
    #pragma unroll
    for (int cb = 0; cb < 4; ++cb) acc[cb] = f32x4{0.f, 0.f, 0.f, 0.f};
    for (int k0 = 0; k0 < CC; k0 += 32) {
        bf16x8 af = ldb8(arow + k0);
        #pragma unroll
        for (int cb = 0; cb < 4; ++cb)
            acc[cb] = mfma16(af, ldb8(brow + (size_t)cb * 16 * CC + k0), acc[cb]);
    }
    int b = row0 / NN, nb = row0 % NN;
    #pragma unroll
    for (int cb = 0; cb < 4; ++cb) {
        int jj = ct * 64 + cb * 16 + q;
        #pragma unroll
        for (int r = 0; r < 4; ++r) {
            int n = nb + 4 * g + r;
            unsigned short bv = f2bf(acc[cb][r]);
            if (jj < 256) {
                int h = jj >> 5, c = jj & 31;
                qbh[(size_t)((b * NH + h) * NN + n) * DD + c] = bv;
            } else if (jj < 512) {
                int jk = jj - 256; int h = jk >> 5, c = jk & 31;
                kbh[(size_t)((b * NH + h) * NN + n) * DD + c] = bv;
            } else {
                int jv = jj - 512; int h = jv >> 5, c = jv & 31;
                v2pT[(size_t)((b * NH + h) * VW + c) * NN + n] = bv;
            }
        }
    }
}

// ---------------------------------------------------------------------------
// fused attention: block = 2 INDEPENDENT waves (no barriers), each wave owns
// 16 q-rows x full m. Pass A: l = sum exp2(s*C). Pass B: recompute S^T,
// p(bf16) -> private [16][512] LDS tile (XOR-swizzled), PV-MFMA from tile;
// every 512 m a store burst writes 16 rows x 2KB CONTIGUOUS f32 NT stores
// (tests HBM page-locality theory: 2KB chunks vs R5's 1KB).
// ---------------------------------------------------------------------------
__global__ __launch_bounds__(128) void attn_kernel(
    const unsigned short* __restrict__ qbh, const unsigned short* __restrict__ kbh,
    const unsigned short* __restrict__ v2pT,
    float* __restrict__ out, unsigned short* __restrict__ yacc)
{
    __shared__ unsigned short ptile[2][16][512];   // 32 KB/block
    const float C = 0.17677669529663687f * 1.4426950408889634f;  // scale*log2e

    int bh = blockIdx.x;        // 0..15
    int qt = blockIdx.y;        // 0..95
    int wv = threadIdx.x >> 6, lane = threadIdx.x & 63;
    int g = lane >> 4, q = lane & 15;
    int qrow = qt * 32 + wv * 16;

    bf16x8 qf = ldb8(qbh + (size_t)(bh * NN + qrow + q) * DD + g * 8);
    const unsigned short* kbase = kbh + (size_t)bh * NN * DD;
    const unsigned short* vbase = v2pT + (size_t)bh * VW * NN;

    // ---- pass A: row sums of exp ----
    float l = 0.f;
    {
        bf16x8 kf0 = ldb8(kbase + (size_t)(q) * DD + g * 8);
        bf16x8 kf1 = ldb8(kbase + (size_t)(16 + q) * DD + g * 8);
        for (int it = 0; it < 96; ++it) {
            int m0 = it * 32;
            bf16x8 kn0 = ldb8(kbase + (size_t)(m0 + 32 + q) * DD + g * 8);
            bf16x8 kn1 = ldb8(kbase + (size_t)(m0 + 48 + q) * DD + g * 8);
            f32x4 z = {0.f, 0.f, 0.f, 0.f};
            f32x4 s0 = mfma16(kf0, qf, z);
            f32x4 s1 = mfma16(kf1, qf, z);
            #pragma unroll
            for (int r = 0; r < 4; ++r)
                l += exp2f(s0[r] * C) + exp2f(s1[r] * C);
            kf0 = kn0; kf1 = kn1;
        }
    }
    l += __shfl_xor(l, 16, 64);
    l += __shfl_xor(l, 32, 64);
    float nl2 = -__log2f(l);                  // p = exp2(s*C + nl2)

    // ---- pass B ----
    f32x4 yt0 = {0.f,0.f,0.f,0.f}, yt1 = yt0, yt2 = yt0;
    char* myt = (char*)&ptile[wv][0][0];         // 16 rows x 1024 B
    char* prow = myt + q * 1024;                 // this thread's write row
    unsigned swq = (unsigned)((q & 7) << 4);     // bank swizzle (XOR bits 4..6)

    bf16x8 kf0 = ldb8(kbase + (size_t)(q) * DD + g * 8);
    bf16x8 kf1 = ldb8(kbase + (size_t)(16 + q) * DD + g * 8);
    bf16x8 vf0 = ldb8(vbase + (size_t)(q) * NN + g * 8);
    bf16x8 vf1 = ldb8(vbase + (size_t)(16 + q) * NN + g * 8);
    bf16x8 vf2 = ldb8(vbase + (size_t)(32 + q) * NN + g * 8);

    for (int ph = 0; ph < 6; ++ph) {
        #pragma unroll 4
        for (int it2 = 0; it2 < 16; ++it2) {
            int m0 = ph * 512 + it2 * 32;
            // prefetch next-iter K and V (tail reads stay inside ws: ok)
            bf16x8 kn0 = ldb8(kbase + (size_t)(m0 + 32 + q) * DD + g * 8);
            bf16x8 kn1 = ldb8(kbase + (size_t)(m0 + 48 + q) * DD + g * 8);
            bf16x8 vn0 = ldb8(vbase + (size_t)(q) * NN + m0 + 32 + g * 8);
            bf16x8 vn1 = ldb8(vbase + (size_t)(16 + q) * NN + m0 + 32 + g * 8);
            bf16x8 vn2 = ldb8(vbase + (size_t)(32 + q) * NN + m0 + 32 + g * 8);

            f32x4 z = {0.f, 0.f, 0.f, 0.f};
            f32x4 s0 = mfma16(kf0, qf, z);
            f32x4 s1 = mfma16(kf1, qf, z);
            short4v pk0, pk1;
            #pragma unroll
            for (int r = 0; r < 4; ++r) {
                pk0[r] = (short)f2bf(exp2f(__builtin_fmaf(s0[r], C, nl2)));
                pk1[r] = (short)f2bf(exp2f(__builtin_fmaf(s1[r], C, nl2)));
            }
            // LDS tile write: p0 at bytes it2*64+8g, p1 at +32 (swizzled)
            unsigned b0 = (unsigned)(it2 * 64 + 8 * g);
            *(short4v*)(prow + (b0 ^ swq)) = pk0;
            *(short4v*)(prow + ((b0 + 32) ^ swq)) = pk1;
            asm volatile("s_waitcnt lgkmcnt(0)" ::: "memory");
            __builtin_amdgcn_sched_barrier(0);
            // PV fragment read: 16B at it2*64+16g (swizzled, stays 16B-aligned)
            bf16x8 pf = *(const bf16x8*)(prow + ((unsigned)(it2 * 64 + 16 * g) ^ swq));
            yt0 = mfma16(vf0, pf, yt0);
            yt1 = mfma16(vf1, pf, yt1);
            yt2 = mfma16(vf2, pf, yt2);
            kf0 = kn0; kf1 = kn1; vf0 = vn0; vf1 = vn1; vf2 = vn2;
        }
        // ---- store burst: 16 rows x 2KB contiguous (2x 1KB instrs) ----
        #pragma unroll
        for (int i = 0; i < 16; ++i) {
            unsigned swi = (unsigned)((i & 7) << 4);
            float* rdst = out + (size_t)(bh * NN + qrow + i) * OUTW + ph * 512;
            #pragma unroll
            for (int j = 0; j < 2; ++j) {
                unsigned off = ((unsigned)(j * 512 + lane * 8)) ^ swi;
                unsigned long long d = *(const unsigned long long*)(myt + i * 1024 + off);
                unsigned dlo = (unsigned)d, dhi = (unsigned)(d >> 32);
                f32x4 v;
                v[0] = bflo2f(dlo); v[1] = bfhi2f(dlo);
                v[2] = bflo2f(dhi); v[3] = bfhi2f(dhi);
                __builtin_nontemporal_store(v, (f32x4*)(rdst + j * 256 + lane * 4));
            }
        }
    }

    // ---- epilogue: y^T frag -> yacc[b*NN+n][h*48 + c] bf16 ----
    int b = bh >> 3, h = bh & 7;
    int nrow = qrow + q;
    unsigned short* yrow = yacc + (size_t)(b * NN + nrow) * KP + h * VW;
    f32x4 yts[3] = { yt0, yt1, yt2 };
    #pragma unroll
    for (int cb = 0; cb < 3; ++cb) {
        short4v pk;
        #pragma unroll
        for (int r = 0; r < 4; ++r) pk[r] = (short)f2bf(yts[cb][r]);
        *(short4v*)(yrow + cb * 16 + 4 * g) = pk;
    }
}

// ---------------------------------------------------------------------------
// proj
// ---------------------------------------------------------------------------
__global__ __launch_bounds__(256) void proj_kernel(
    const unsigned short* __restrict__ yacc, const unsigned short* __restrict__ Wpft,
    const float* __restrict__ bpf, float* __restrict__ out)
{
    int rt = blockIdx.x, ct = blockIdx.y;
    int wv = threadIdx.x >> 6, lane = threadIdx.x & 63;
    int g = lane >> 4, q = lane & 15;
    int row0 = rt * 64 + wv * 16;
    const unsigned short* arow = yacc + (size_t)(row0 + q) * KP + g * 8;
    const unsigned short* b0 = Wpft + (size_t)(ct * 64 + q) * KP + g * 8;
    f32x4 acc[4];
    #pragma unroll
    for (int cb = 0; cb < 4; ++cb) acc[cb] = f32x4{0.f, 0.f, 0.f, 0.f};
    for (int k0 = 0; k0 < KP; k0 += 32) {
        bf16x8 af = ldb8(arow + k0);
        #pragma unroll
        for (int cb = 0; cb < 4; ++cb)
            acc[cb] = mfma16(af, ldb8(b0 + (size_t)cb * 16 * KP + k0), acc[cb]);
    }
    int b = row0 / NN, nb = row0 % NN;
    #pragma unroll
    for (int cb = 0; cb < 4; ++cb) {
        int c2 = ct * 64 + cb * 16 + q;
        float bias = bpf[c2];
        int h = c2 >> 5, c = c2 & 31;
        float* obase = out + (size_t)((b * NH + h) * NN) * OUTW + NN + c;
        #pragma unroll
        for (int r = 0; r < 4; ++r) {
            int n = nb + 4 * g + r;
            __builtin_nontemporal_store(acc[cb][r] + bias, &obase[(size_t)n * OUTW]);
        }
    }
}

// ---------------------------------------------------------------------------
extern "C" void kernel_launch(void* const* d_in, const int* in_sizes, int n_in,
                              void* d_out, int out_size, void* d_ws, size_t ws_size,
                              hipStream_t stream)
{
    (void)in_sizes; (void)n_in; (void)out_size; (void)ws_size;
    const float* x1  = (const float*)d_in[0];
    const float* x2  = (const float*)d_in[1];
    const float* Wq  = (const float*)d_in[2];
    const float* Wkv = (const float*)d_in[3];
    const float* Wpf = (const float*)d_in[4];
    const float* bpf = (const float*)d_in[5];
    float* out = (float*)d_out;
    char* ws = (char*)d_ws;

    unsigned short* x1b  = (unsigned short*)(ws + 0);
    unsigned short* x2b  = (unsigned short*)(ws + 3145728);
    unsigned short* Wt   = (unsigned short*)(ws + 6291456);
    unsigned short* Wpft = (unsigned short*)(ws + 6684672);
    unsigned short* qbh  = (unsigned short*)(ws + 6881280);
    unsigned short* kbh  = (unsigned short*)(ws + 10027008);
    unsigned short* v2pT = (unsigned short*)(ws + 13172736);
    unsigned short* yacc = (unsigned short*)(ws + 17891328);

    prep_kernel<<<16512, 256, 0, stream>>>(x1, x2, Wq, Wkv, Wpf, x1b, x2b, Wt, Wpft, v2pT);
    qkv_kernel<<<dim3(96, 12), 256, 0, stream>>>(x1b, x2b, Wt, qbh, kbh, v2pT);
    attn_kernel<<<dim3(16, 96), 128, 0, stream>>>(qbh, kbh, v2pT, out, yacc);
    proj_kernel<<<dim3(96, 4), 256, 0, stream>>>(yacc, Wpft, bpf, out);
}

// Round 7
// 240.692 us; speedup vs baseline: 1.2547x; 1.2547x over previous
//
#include <hip/hip_runtime.h>
#include <hip/hip_bf16.h>
#include <cstdint>
#include <cstddef>

#define NB 2
#define NH 8
#define BHN 16          // NB*NH
#define NN 3072         // tokens
#define CC 256          // channels
#define DD 32           // head dim
#define OUTW 3104       // NN + DD
#define VW 48           // padded v2p width (38 -> 48)
#define KP 384          // NH*VW, padded K for proj GEMM

typedef __attribute__((ext_vector_type(8))) __bf16 bf16x8;
typedef __attribute__((ext_vector_type(4))) short short4v;
typedef __attribute__((ext_vector_type(4))) float f32x4;

static __device__ __forceinline__ unsigned short f2bf(float f) {
    __hip_bfloat16 h = __float2bfloat16(f);
    return *reinterpret_cast<unsigned short*>(&h);
}

static __device__ __forceinline__ bf16x8 ldb8(const unsigned short* p) {
    return *(const bf16x8*)p;
}

static __device__ __forceinline__ f32x4 mfma16(bf16x8 a, bf16x8 b, f32x4 c) {
    return __builtin_amdgcn_mfma_f32_16x16x32_bf16(a, b, c, 0, 0, 0);
}

static __device__ __forceinline__ float bfhi2f(unsigned u) {
    union { unsigned u; float f; } v; v.u = u & 0xffff0000u; return v.f;
}
static __device__ __forceinline__ float bflo2f(unsigned u) {
    union { unsigned u; float f; } v; v.u = u << 16; return v.f;
}

// ---------------------------------------------------------------------------
// prep
// ---------------------------------------------------------------------------
__global__ __launch_bounds__(256) void prep_kernel(
    const float* __restrict__ x1, const float* __restrict__ x2,
    const float* __restrict__ Wq, const float* __restrict__ Wkv,
    const float* __restrict__ Wpf,
    unsigned short* __restrict__ x1b, unsigned short* __restrict__ x2b,
    unsigned short* __restrict__ Wt, unsigned short* __restrict__ Wpft,
    unsigned short* __restrict__ v2pT)
{
    int i = blockIdx.x * 256 + threadIdx.x;
    const int S_X = NB * NN * CC;
    if (i < S_X) { x1b[i] = f2bf(x1[i]); return; }
    i -= S_X;
    if (i < S_X) { x2b[i] = f2bf(x2[i]); return; }
    i -= S_X;
    const int S_WT = 768 * CC;
    if (i < S_WT) {
        int j = i >> 8, kk = i & 255;
        float w = (j < 256) ? Wq[kk * 256 + j] : Wkv[kk * 512 + (j - 256)];
        Wt[i] = f2bf(w);
        return;
    }
    i -= S_WT;
    const int S_WP = 256 * KP;
    if (i < S_WP) {
        int c2 = i / KP, t = i - c2 * KP;
        int h = t / VW, cc = t - h * VW;
        unsigned short v = 0;
        if (cc < 38) v = f2bf(Wpf[(h * 38 + cc) * 256 + c2]);
        Wpft[i] = v;
        return;
    }
    i -= S_WP;
    const int S_POS = BHN * 16 * NN;
    if (i < S_POS) {
        int n = i % NN;
        int r = i / NN;
        int bh = r >> 4;
        int c = (r & 15) + 32;
        float val = 0.f;
        if (c < 38) {
            float p3 = -1.f + 2.f * (float)(n % 48) / 47.f;
            float p4 = -1.f + 2.f * (float)(n / 48) / 63.f;
            float pv[6] = { p3 * p3, p4 * p4, p3 * p4, p3, p4, 1.f };
            val = pv[c - 32];
        }
        v2pT[((size_t)bh * VW + c) * NN + n] = f2bf(val);
    }
}

// ---------------------------------------------------------------------------
// qkv
// ---------------------------------------------------------------------------
__global__ __launch_bounds__(256) void qkv_kernel(
    const unsigned short* __restrict__ x1b, const unsigned short* __restrict__ x2b,
    const unsigned short* __restrict__ Wt,
    unsigned short* __restrict__ qbh, unsigned short* __restrict__ kbh,
    unsigned short* __restrict__ v2pT)
{
    int rt = blockIdx.x, ct = blockIdx.y;
    int wv = threadIdx.x >> 6, lane = threadIdx.x & 63;
    int g = lane >> 4, q = lane & 15;
    int row0 = rt * 64 + wv * 16;
    const unsigned short* A = (ct < 4) ? x1b : x2b;
    const unsigned short* arow = A + (size_t)(row0 + q) * CC + g * 8;
    const unsigned short* brow = Wt + (size_t)(ct * 64 + q) * CC + g * 8;
    f32x4 acc[4];
    #pragma unroll
    for (int cb = 0; cb < 4; ++cb) acc[cb] = f32x4{0.f, 0.f, 0.f, 0.f};
    for (int k0 = 0; k0 < CC; k0 += 32) {
        bf16x8 af = ldb8(arow + k0);
        #pragma unroll
        for (int cb = 0; cb < 4; ++cb)
            acc[cb] = mfma16(af, ldb8(brow + (size_t)cb * 16 * CC + k0), acc[cb]);
    }
    int b = row0 / NN, nb = row0 % NN;
    #pragma unroll
    for (int cb = 0; cb < 4; ++cb) {
        int jj = ct * 64 + cb * 16 + q;
        #pragma unroll
        for (int r = 0; r < 4; ++r) {
            int n = nb + 4 * g + r;
            unsigned short bv = f2bf(acc[cb][r]);
            if (jj < 256) {
                int h = jj >> 5, c = jj & 31;
                qbh[(size_t)((b * NH + h) * NN + n) * DD + c] = bv;
            } else if (jj < 512) {
                int jk = jj - 256; int h = jk >> 5, c = jk & 31;
                kbh[(size_t)((b * NH + h) * NN + n) * DD + c] = bv;
            } else {
                int jv = jj - 512; int h = jv >> 5, c = jv & 31;
                v2pT[(size_t)((b * NH + h) * VW + c) * NN + n] = bv;
            }
        }
    }
}

// ---------------------------------------------------------------------------
// fused attention: block = (bh, qt); 4 independent waves x 16 q-rows, each
// wave owns the FULL m range (no cross-wave reduces, no barriers).
// XCD-swizzled 1D grid: each XCD owns exactly 2 bh -> K/V (960 KB) stays
// L2-resident, taking the read stream off the L3/fabric (the single
// variable under test this round vs R5's 241 us).
// Pass A: l = sum exp2(s*C). Pass B: recompute S^T, p(bf16) -> [16][256]
// LDS tile (XOR-swizzled), PV-MFMA from tile; every 256 m a store burst
// writes 16 rows x 1KB contiguous f32 NT stores.
// ---------------------------------------------------------------------------
__global__ __launch_bounds__(256) void attn_kernel(
    const unsigned short* __restrict__ qbh, const unsigned short* __restrict__ kbh,
    const unsigned short* __restrict__ v2pT,
    float* __restrict__ out, unsigned short* __restrict__ yacc)
{
    __shared__ unsigned short ptile[4][16][256];   // 32 KB, per-wave [16][256]
    const float C = 0.17677669529663687f * 1.4426950408889634f;  // scale*log2e

    // XCD-bijective swizzle: id%8 = XCD (round-robin dispatch), 768%8==0
    int id = blockIdx.x;
    int xcd = id & 7;
    int slot = id >> 3;                 // 0..95, all resident per XCD
    int bh = xcd * 2 + (slot & 1);      // 0..15: 2 bh per XCD
    int qt = slot >> 1;                 // 0..47

    int wv = threadIdx.x >> 6, lane = threadIdx.x & 63;
    int g = lane >> 4, q = lane & 15;
    int qrow = qt * 64 + wv * 16;

    bf16x8 qf = ldb8(qbh + (size_t)(bh * NN + qrow + q) * DD + g * 8);
    const unsigned short* kbase = kbh + (size_t)bh * NN * DD;
    const unsigned short* vbase = v2pT + (size_t)bh * VW * NN;

    // ---- pass A: row sums of exp ----
    float l = 0.f;
    {
        bf16x8 kf0 = ldb8(kbase + (size_t)(q) * DD + g * 8);
        bf16x8 kf1 = ldb8(kbase + (size_t)(16 + q) * DD + g * 8);
        for (int it = 0; it < 96; ++it) {
            int m0 = it * 32;
            bf16x8 kn0 = ldb8(kbase + (size_t)(m0 + 32 + q) * DD + g * 8);
            bf16x8 kn1 = ldb8(kbase + (size_t)(m0 + 48 + q) * DD + g * 8);
            f32x4 z = {0.f, 0.f, 0.f, 0.f};
            f32x4 s0 = mfma16(kf0, qf, z);
            f32x4 s1 = mfma16(kf1, qf, z);
            #pragma unroll
            for (int r = 0; r < 4; ++r)
                l += exp2f(s0[r] * C) + exp2f(s1[r] * C);
            kf0 = kn0; kf1 = kn1;
        }
    }
    l += __shfl_xor(l, 16, 64);
    l += __shfl_xor(l, 32, 64);
    float nl2 = -__log2f(l);                  // p = exp2(s*C + nl2)

    // ---- pass B ----
    f32x4 yt0 = {0.f,0.f,0.f,0.f}, yt1 = yt0, yt2 = yt0;
    char* myt = (char*)&ptile[wv][0][0];         // 16 rows x 512 B
    char* prow = myt + q * 512;                  // this thread's write row
    unsigned swq = (unsigned)((q & 7) << 4);     // bank swizzle (XOR bytes 4..6)

    bf16x8 kf0 = ldb8(kbase + (size_t)(q) * DD + g * 8);
    bf16x8 kf1 = ldb8(kbase + (size_t)(16 + q) * DD + g * 8);
    bf16x8 vf0 = ldb8(vbase + (size_t)(q) * NN + g * 8);
    bf16x8 vf1 = ldb8(vbase + (size_t)(16 + q) * NN + g * 8);
    bf16x8 vf2 = ldb8(vbase + (size_t)(32 + q) * NN + g * 8);

    for (int ph = 0; ph < 12; ++ph) {
        #pragma unroll
        for (int it2 = 0; it2 < 8; ++it2) {
            int m0 = ph * 256 + it2 * 32;
            // prefetch next-iter K and V (tail reads stay inside ws: ok)
            bf16x8 kn0 = ldb8(kbase + (size_t)(m0 + 32 + q) * DD + g * 8);
            bf16x8 kn1 = ldb8(kbase + (size_t)(m0 + 48 + q) * DD + g * 8);
            bf16x8 vn0 = ldb8(vbase + (size_t)(q) * NN + m0 + 32 + g * 8);
            bf16x8 vn1 = ldb8(vbase + (size_t)(16 + q) * NN + m0 + 32 + g * 8);
            bf16x8 vn2 = ldb8(vbase + (size_t)(32 + q) * NN + m0 + 32 + g * 8);

            f32x4 z = {0.f, 0.f, 0.f, 0.f};
            f32x4 s0 = mfma16(kf0, qf, z);
            f32x4 s1 = mfma16(kf1, qf, z);
            short4v pk0, pk1;
            #pragma unroll
            for (int r = 0; r < 4; ++r) {
                pk0[r] = (short)f2bf(exp2f(__builtin_fmaf(s0[r], C, nl2)));
                pk1[r] = (short)f2bf(exp2f(__builtin_fmaf(s1[r], C, nl2)));
            }
            // LDS tile write: p0 at bytes it2*64+8g, p1 at +32 (swizzled)
            unsigned b0 = (unsigned)(it2 * 64 + 8 * g);
            *(short4v*)(prow + (b0 ^ swq)) = pk0;
            *(short4v*)(prow + ((b0 + 32) ^ swq)) = pk1;
            asm volatile("s_waitcnt lgkmcnt(0)" ::: "memory");
            __builtin_amdgcn_sched_barrier(0);
            // PV fragment read: bytes it2*64+16g .. +15 (swizzled, 16B-aligned)
            bf16x8 pf = *(const bf16x8*)(prow + ((unsigned)(it2 * 64 + 16 * g) ^ swq));
            yt0 = mfma16(vf0, pf, yt0);
            yt1 = mfma16(vf1, pf, yt1);
            yt2 = mfma16(vf2, pf, yt2);
            kf0 = kn0; kf1 = kn1; vf0 = vn0; vf1 = vn1; vf2 = vn2;
        }
        // ---- store burst: 16 rows x 1KB contiguous NT stores ----
        #pragma unroll
        for (int i = 0; i < 16; ++i) {
            unsigned off = ((unsigned)(lane * 8)) ^ ((unsigned)((i & 7) << 4));
            uint2 d = *(const uint2*)(myt + i * 512 + off);
            f32x4 v;
            v[0] = bflo2f(d.x); v[1] = bfhi2f(d.x);
            v[2] = bflo2f(d.y); v[3] = bfhi2f(d.y);
            float* dst = out + (size_t)(bh * NN + qrow + i) * OUTW + ph * 256 + lane * 4;
            __builtin_nontemporal_store(v, (f32x4*)dst);
        }
    }

    // ---- epilogue: y^T frag -> yacc[b*NN+n][h*48 + c] bf16 ----
    int b = bh >> 3, h = bh & 7;
    int nrow = qrow + q;
    unsigned short* yrow = yacc + (size_t)(b * NN + nrow) * KP + h * VW;
    f32x4 yts[3] = { yt0, yt1, yt2 };
    #pragma unroll
    for (int cb = 0; cb < 3; ++cb) {
        short4v pk;
        #pragma unroll
        for (int r = 0; r < 4; ++r) pk[r] = (short)f2bf(yts[cb][r]);
        *(short4v*)(yrow + cb * 16 + 4 * g) = pk;
    }
}

// ---------------------------------------------------------------------------
// proj
// ---------------------------------------------------------------------------
__global__ __launch_bounds__(256) void proj_kernel(
    const unsigned short* __restrict__ yacc, const unsigned short* __restrict__ Wpft,
    const float* __restrict__ bpf, float* __restrict__ out)
{
    int rt = blockIdx.x, ct = blockIdx.y;
    int wv = threadIdx.x >> 6, lane = threadIdx.x & 63;
    int g = lane >> 4, q = lane & 15;
    int row0 = rt * 64 + wv * 16;
    const unsigned short* arow = yacc + (size_t)(row0 + q) * KP + g * 8;
    const unsigned short* b0 = Wpft + (size_t)(ct * 64 + q) * KP + g * 8;
    f32x4 acc[4];
    #pragma unroll
    for (int cb = 0; cb < 4; ++cb) acc[cb] = f32x4{0.f, 0.f, 0.f, 0.f};
    for (int k0 = 0; k0 < KP; k0 += 32) {
        bf16x8 af = ldb8(arow + k0);
        #pragma unroll
        for (int cb = 0; cb < 4; ++cb)
            acc[cb] = mfma16(af, ldb8(b0 + (size_t)cb * 16 * KP + k0), acc[cb]);
    }
    int b = row0 / NN, nb = row0 % NN;
    #pragma unroll
    for (int cb = 0; cb < 4; ++cb) {
        int c2 = ct * 64 + cb * 16 + q;
        float bias = bpf[c2];
        int h = c2 >> 5, c = c2 & 31;
        float* obase = out + (size_t)((b * NH + h) * NN) * OUTW + NN + c;
        #pragma unroll
        for (int r = 0; r < 4; ++r) {
            int n = nb + 4 * g + r;
            __builtin_nontemporal_store(acc[cb][r] + bias, &obase[(size_t)n * OUTW]);
        }
    }
}

// ---------------------------------------------------------------------------
extern "C" void kernel_launch(void* const* d_in, const int* in_sizes, int n_in,
                              void* d_out, int out_size, void* d_ws, size_t ws_size,
                              hipStream_t stream)
{
    (void)in_sizes; (void)n_in; (void)out_size; (void)ws_size;
    const float* x1  = (const float*)d_in[0];
    const float* x2  = (const float*)d_in[1];
    const float* Wq  = (const float*)d_in[2];
    const float* Wkv = (const float*)d_in[3];
    const float* Wpf = (const float*)d_in[4];
    const float* bpf = (const float*)d_in[5];
    float* out = (float*)d_out;
    char* ws = (char*)d_ws;

    unsigned short* x1b  = (unsigned short*)(ws + 0);
    unsigned short* x2b  = (unsigned short*)(ws + 3145728);
    unsigned short* Wt   = (unsigned short*)(ws + 6291456);
    unsigned short* Wpft = (unsigned short*)(ws + 6684672);
    unsigned short* qbh  = (unsigned short*)(ws + 6881280);
    unsigned short* kbh  = (unsigned short*)(ws + 10027008);
    unsigned short* v2pT = (unsigned short*)(ws + 13172736);
    unsigned short* yacc = (unsigned short*)(ws + 17891328);

    prep_kernel<<<16512, 256, 0, stream>>>(x1, x2, Wq, Wkv, Wpf, x1b, x2b, Wt, Wpft, v2pT);
    qkv_kernel<<<dim3(96, 12), 256, 0, stream>>>(x1b, x2b, Wt, qbh, kbh, v2pT);
    attn_kernel<<<768, 256, 0, stream>>>(qbh, kbh, v2pT, out, yacc);
    proj_kernel<<<dim3(96, 4), 256, 0, stream>>>(yacc, Wpft, bpf, out);
}